// Round 1
// 449.179 us; speedup vs baseline: 1.1693x; 1.1693x over previous
//
#include <hip/hip_runtime.h>

// GCN layer: out = leaky_relu( segment_sum(edge_vals[:,None] * embeds[col], row, N), 0.5 )
// E = 3.2M, N = 100000, D = 128, f32.
//
// R3: (a) pack per-edge chain metadata into ONE 16B node {next, col, val, pad}
//     written contiguously at build time -> 1 broadcast line per hop instead of
//     3 scattered line fetches (next/col/val in separate arrays).
//     (b) 4 parity chains per row chased concurrently, branch-free -> serial
//     pointer-chase depth 32 -> ~13, 4x memory-level parallelism per wave.
// Reduce: one wave per row; lane owns 2 consecutive f32 columns; fused
// leaky_relu; single 512 B coalesced store.

#define GCN_D       128
#define LEAKY_SLOPE 0.5f
#define NCHAIN      4

// ---------------- R3 fast path: packed nodes + 4-way chain reduce ----------------

__global__ void build_nodes_kernel(const int* __restrict__ row,
                                   const int* __restrict__ col,
                                   const float* __restrict__ val,
                                   int E,
                                   int* __restrict__ head,
                                   int4* __restrict__ node) {
    int stride = gridDim.x * blockDim.x;
    for (int i = blockIdx.x * blockDim.x + threadIdx.x; i < E; i += stride) {
        int   r = row[i];
        int   c = col[i];
        float v = val[i];
        // 4 independent chains per row, split by edge-index parity.
        int prev = atomicExch(&head[r * NCHAIN + (i & (NCHAIN - 1))], i);
        // Contiguous 16B store: {next, col, val_bits, pad}
        node[i] = make_int4(prev, c, __float_as_int(v), 0);
    }
}

// One wave (64 lanes) per output row; lane owns 2 consecutive f32 columns.
// Chases NCHAIN=4 chains simultaneously, branch-free (dead chains clamp to
// node[0] / embeds row 0 -> permanently cache-hot, accumulate 0).
__global__ void __launch_bounds__(256)
reduce_nodes_kernel(const int* __restrict__ head,
                    const int4* __restrict__ node,
                    const float* __restrict__ embeds,
                    float* __restrict__ out,
                    int N) {
    int wave = (int)((blockIdx.x * (long long)blockDim.x + threadIdx.x) >> 6);
    int lane = threadIdx.x & 63;
    if (wave >= N) return;

    const float2* eb = reinterpret_cast<const float2*>(embeds);

    // head is [N][NCHAIN] ints, 16B-aligned -> one broadcast int4 load.
    int4 h = reinterpret_cast<const int4*>(head)[wave];
    int e0 = h.x, e1 = h.y, e2 = h.z, e3 = h.w;

    float ax = 0.f, ay = 0.f;

    // (e0 & e1 & e2 & e3) == -1  iff  all four chains are exhausted.
    while ((e0 & e1 & e2 & e3) != -1) {
        int i0 = e0 >= 0 ? e0 : 0;
        int i1 = e1 >= 0 ? e1 : 0;
        int i2 = e2 >= 0 ? e2 : 0;
        int i3 = e3 >= 0 ? e3 : 0;

        // 4 independent broadcast 16B loads -> all in flight together.
        int4 n0 = node[i0];
        int4 n1 = node[i1];
        int4 n2 = node[i2];
        int4 n3 = node[i3];

        int c0 = e0 >= 0 ? n0.y : 0;
        int c1 = e1 >= 0 ? n1.y : 0;
        int c2 = e2 >= 0 ? n2.y : 0;
        int c3 = e3 >= 0 ? n3.y : 0;

        // 4 independent coalesced 512 B gathers.
        float2 m0 = eb[(long long)c0 * 64 + lane];
        float2 m1 = eb[(long long)c1 * 64 + lane];
        float2 m2 = eb[(long long)c2 * 64 + lane];
        float2 m3 = eb[(long long)c3 * 64 + lane];

        float v0 = e0 >= 0 ? __int_as_float(n0.z) : 0.f;
        float v1 = e1 >= 0 ? __int_as_float(n1.z) : 0.f;
        float v2 = e2 >= 0 ? __int_as_float(n2.z) : 0.f;
        float v3 = e3 >= 0 ? __int_as_float(n3.z) : 0.f;

        ax += v0 * m0.x; ay += v0 * m0.y;
        ax += v1 * m1.x; ay += v1 * m1.y;
        ax += v2 * m2.x; ay += v2 * m2.y;
        ax += v3 * m3.x; ay += v3 * m3.y;

        e0 = e0 >= 0 ? n0.x : -1;
        e1 = e1 >= 0 ? n1.x : -1;
        e2 = e2 >= 0 ? n2.x : -1;
        e3 = e3 >= 0 ? n3.x : -1;
    }

    ax = ax > 0.f ? ax : LEAKY_SLOPE * ax;
    ay = ay > 0.f ? ay : LEAKY_SLOPE * ay;
    reinterpret_cast<float2*>(out)[(long long)wave * 64 + lane] =
        make_float2(ax, ay);
}

// ---------------- R2 fallback: separate next[] linked list ----------------

__global__ void build_chain_kernel(const int* __restrict__ row, int E,
                                   int* __restrict__ head,
                                   int* __restrict__ next) {
    int stride = gridDim.x * blockDim.x;
    for (int i = blockIdx.x * blockDim.x + threadIdx.x; i < E; i += stride) {
        int r = row[i];
        next[i] = atomicExch(&head[r], i);
    }
}

__global__ void reduce_chain_kernel(const int* __restrict__ head,
                                    const int* __restrict__ next,
                                    const int* __restrict__ col,
                                    const float* __restrict__ val,
                                    const float* __restrict__ embeds,
                                    float* __restrict__ out,
                                    int N) {
    int wave = (int)((blockIdx.x * (long long)blockDim.x + threadIdx.x) >> 6);
    int lane = threadIdx.x & 63;
    if (wave >= N) return;

    const float2* eb = reinterpret_cast<const float2*>(embeds);
    float ax = 0.f, ay = 0.f;

    int e = head[wave];
    while (e >= 0) {
        int   ne = next[e];
        int   c  = col[e];
        float v  = val[e];
        float2 m = eb[(long long)c * 64 + lane];
        ax += v * m.x;
        ay += v * m.y;
        e = ne;
    }

    ax = ax > 0.f ? ax : LEAKY_SLOPE * ax;
    ay = ay > 0.f ? ay : LEAKY_SLOPE * ay;
    reinterpret_cast<float2*>(out)[(long long)wave * 64 + lane] =
        make_float2(ax, ay);
}

// ---------------- R0 fallback: atomic scatter ----------------

__global__ void gcn_scatter_kernel(const int* __restrict__ row_idx,
                                   const int* __restrict__ col_idx,
                                   const float* __restrict__ vals,
                                   const float* __restrict__ embeds,
                                   float* __restrict__ out,
                                   int E) {
    long long tid = (long long)blockIdx.x * blockDim.x + threadIdx.x;
    long long e = tid >> 5;
    if (e >= E) return;
    int q = (int)(tid & 31);
    int row = row_idx[e];
    int col = col_idx[e];
    float v = vals[e];
    const float4* src =
        reinterpret_cast<const float4*>(embeds + (long long)col * GCN_D) + q;
    float4 m = *src;
    float* dst = out + (long long)row * GCN_D + (long long)q * 4;
    atomicAdd(dst + 0, v * m.x);
    atomicAdd(dst + 1, v * m.y);
    atomicAdd(dst + 2, v * m.z);
    atomicAdd(dst + 3, v * m.w);
}

__global__ void gcn_leaky_relu_kernel(float* __restrict__ out, int n4) {
    int i = blockIdx.x * blockDim.x + threadIdx.x;
    if (i >= n4) return;
    float4* p = reinterpret_cast<float4*>(out) + i;
    float4 x = *p;
    x.x = x.x > 0.f ? x.x : LEAKY_SLOPE * x.x;
    x.y = x.y > 0.f ? x.y : LEAKY_SLOPE * x.y;
    x.z = x.z > 0.f ? x.z : LEAKY_SLOPE * x.z;
    x.w = x.w > 0.f ? x.w : LEAKY_SLOPE * x.w;
    *p = x;
}

// ---------------------------------------------------------------------------

extern "C" void kernel_launch(void* const* d_in, const int* in_sizes, int n_in,
                              void* d_out, int out_size, void* d_ws, size_t ws_size,
                              hipStream_t stream) {
    const int*   edge_index = (const int*)d_in[0];   // (2, E) flat, int32
    const float* edge_vals  = (const float*)d_in[1]; // (E,)
    const float* embeds     = (const float*)d_in[2]; // (N, 128)
    float*       out        = (float*)d_out;         // (N, 128)

    const int E = in_sizes[1];
    const int N = out_size / GCN_D;                  // 100000
    const int* row = edge_index;
    const int* col = edge_index + E;

    const int block = 256;

    // R3 ws layout: head[N*NCHAIN] | node[E] (int4, 16B)
    size_t need_fast  = (size_t)N * NCHAIN * sizeof(int) + (size_t)E * sizeof(int4);
    // R2 ws layout: head[N] | next[E]
    size_t need_chain = (size_t)N * sizeof(int) + (size_t)E * sizeof(int);

    if (ws_size >= need_fast) {
        int*  head = (int*)d_ws;
        int4* node = reinterpret_cast<int4*>(head + (size_t)N * NCHAIN);

        hipMemsetAsync(head, 0xFF, (size_t)N * NCHAIN * sizeof(int), stream);

        build_nodes_kernel<<<2048, block, 0, stream>>>(row, col, edge_vals,
                                                       E, head, node);

        long long threads = (long long)N * 64;       // one wave per row
        int rblocks = (int)((threads + block - 1) / block);
        reduce_nodes_kernel<<<rblocks, block, 0, stream>>>(
            head, node, embeds, out, N);
    } else if (ws_size >= need_chain) {
        int* head = (int*)d_ws;
        int* next = head + N;

        hipMemsetAsync(head, 0xFF, (size_t)N * sizeof(int), stream);
        build_chain_kernel<<<2048, block, 0, stream>>>(row, E, head, next);

        long long threads = (long long)N * 64;
        int rblocks = (int)((threads + block - 1) / block);
        reduce_chain_kernel<<<rblocks, block, 0, stream>>>(
            head, next, col, edge_vals, embeds, out, N);
    } else {
        hipMemsetAsync(d_out, 0, (size_t)out_size * sizeof(float), stream);
        long long total_threads = (long long)E * 32;
        long long grid = (total_threads + block - 1) / block;
        gcn_scatter_kernel<<<(unsigned)grid, block, 0, stream>>>(
            row, col, edge_vals, embeds, out, E);
        int n4 = out_size / 4;
        gcn_leaky_relu_kernel<<<(n4 + 255) / 256, 256, 0, stream>>>(out, n4);
    }
}

// Round 2
// 425.986 us; speedup vs baseline: 1.2329x; 1.0544x over previous
//
#include <hip/hip_runtime.h>
#include <hip/hip_fp16.h>

// GCN layer: out = leaky_relu( segment_sum(edge_vals[:,None] * embeds[col], row, N), 0.5 )
// E = 3.2M, N = 100000, D = 128, f32 in/out.
//
// R4: reduce is EA-bandwidth-bound (3.5 TB/s on 948 MB of L2-miss traffic).
//     (a) Gather embeds in fp16: conversion pass fused into the build kernel
//         (separate block range, overlaps the atomic-bound chain build).
//         Gather traffic halves (512B -> 256B per edge); fp16 embeds (25.6 MB)
//         gets much better L2 residency. Accuracy: ~1e-3 rms added, vs 0.0625
//         reported tolerance.
//     (b) Non-temporal hints on all streaming traffic (node loads, out stores,
//         conversion reads/writes) so it stops evicting embeds from L2.
// Kept from R3: packed 16B nodes, 4 parity chains per row chased branch-free.

#define GCN_D       128
#define LEAKY_SLOPE 0.5f
#define NCHAIN      4

typedef int   i32x4 __attribute__((ext_vector_type(4)));
typedef float f32x2 __attribute__((ext_vector_type(2)));
typedef float f32x4 __attribute__((ext_vector_type(4)));
typedef unsigned int u32x4 __attribute__((ext_vector_type(4)));

__device__ inline unsigned pack_half2(float a, float b) {
    __half2 h = __floats2half2_rn(a, b);
    return *reinterpret_cast<unsigned*>(&h);
}

// ---------------- R4 fast path ----------------

// Fused: blocks [0, convBlocks) convert embeds f32 -> f16 (streaming, nt);
// blocks [convBlocks, grid) build the 4-parity chain structure.
__global__ void build_convert_kernel(const int* __restrict__ row,
                                     const int* __restrict__ col,
                                     const float* __restrict__ val,
                                     int E,
                                     const f32x4* __restrict__ emb4,  // N*32
                                     int n8,                          // N*16 groups of 8 floats
                                     u32x4* __restrict__ h8,          // N*16 (8 halves each)
                                     int* __restrict__ head,
                                     i32x4* __restrict__ node,
                                     int convBlocks) {
    if ((int)blockIdx.x < convBlocks) {
        int stride = convBlocks * blockDim.x;
        for (int i = blockIdx.x * blockDim.x + threadIdx.x; i < n8; i += stride) {
            f32x4 a = __builtin_nontemporal_load(&emb4[2 * i]);
            f32x4 b = __builtin_nontemporal_load(&emb4[2 * i + 1]);
            u32x4 o;
            o.x = pack_half2(a.x, a.y);
            o.y = pack_half2(a.z, a.w);
            o.z = pack_half2(b.x, b.y);
            o.w = pack_half2(b.z, b.w);
            __builtin_nontemporal_store(o, &h8[i]);
        }
    } else {
        int bid = (int)blockIdx.x - convBlocks;
        int nb  = (int)gridDim.x - convBlocks;
        int stride = nb * blockDim.x;
        for (int i = bid * blockDim.x + threadIdx.x; i < E; i += stride) {
            int   r = row[i];
            int   c = col[i];
            float v = val[i];
            int prev = atomicExch(&head[r * NCHAIN + (i & (NCHAIN - 1))], i);
            i32x4 nd;
            nd.x = prev; nd.y = c; nd.z = __float_as_int(v); nd.w = 0;
            __builtin_nontemporal_store(nd, &node[i]);
        }
    }
}

// One wave per output row; lane owns 2 consecutive columns (half2 gather).
// Chases 4 chains branch-free; dead chains clamp to node[0]/row 0 (hot, v=0).
__global__ void __launch_bounds__(256)
reduce_half_kernel(const int* __restrict__ head,
                   const i32x4* __restrict__ node,
                   const __half2* __restrict__ ebh,   // N*64 half2
                   float* __restrict__ out,
                   int N) {
    int wave = (int)((blockIdx.x * (long long)blockDim.x + threadIdx.x) >> 6);
    int lane = threadIdx.x & 63;
    if (wave >= N) return;

    int4 h = reinterpret_cast<const int4*>(head)[wave];
    int e0 = h.x, e1 = h.y, e2 = h.z, e3 = h.w;

    float ax = 0.f, ay = 0.f;

    while ((e0 & e1 & e2 & e3) != -1) {
        int i0 = e0 >= 0 ? e0 : 0;
        int i1 = e1 >= 0 ? e1 : 0;
        int i2 = e2 >= 0 ? e2 : 0;
        int i3 = e3 >= 0 ? e3 : 0;

        // 4 independent broadcast 16B node loads, non-temporal (read-once).
        i32x4 n0 = __builtin_nontemporal_load(&node[i0]);
        i32x4 n1 = __builtin_nontemporal_load(&node[i1]);
        i32x4 n2 = __builtin_nontemporal_load(&node[i2]);
        i32x4 n3 = __builtin_nontemporal_load(&node[i3]);

        int c0 = e0 >= 0 ? n0.y : 0;
        int c1 = e1 >= 0 ? n1.y : 0;
        int c2 = e2 >= 0 ? n2.y : 0;
        int c3 = e3 >= 0 ? n3.y : 0;

        // 4 independent coalesced 256 B fp16 gathers (want these in L2).
        __half2 m0 = ebh[(long long)c0 * 64 + lane];
        __half2 m1 = ebh[(long long)c1 * 64 + lane];
        __half2 m2 = ebh[(long long)c2 * 64 + lane];
        __half2 m3 = ebh[(long long)c3 * 64 + lane];

        float v0 = e0 >= 0 ? __int_as_float(n0.z) : 0.f;
        float v1 = e1 >= 0 ? __int_as_float(n1.z) : 0.f;
        float v2 = e2 >= 0 ? __int_as_float(n2.z) : 0.f;
        float v3 = e3 >= 0 ? __int_as_float(n3.z) : 0.f;

        float2 f0 = __half22float2(m0);
        float2 f1 = __half22float2(m1);
        float2 f2 = __half22float2(m2);
        float2 f3 = __half22float2(m3);

        ax += v0 * f0.x; ay += v0 * f0.y;
        ax += v1 * f1.x; ay += v1 * f1.y;
        ax += v2 * f2.x; ay += v2 * f2.y;
        ax += v3 * f3.x; ay += v3 * f3.y;

        e0 = e0 >= 0 ? n0.x : -1;
        e1 = e1 >= 0 ? n1.x : -1;
        e2 = e2 >= 0 ? n2.x : -1;
        e3 = e3 >= 0 ? n3.x : -1;
    }

    ax = ax > 0.f ? ax : LEAKY_SLOPE * ax;
    ay = ay > 0.f ? ay : LEAKY_SLOPE * ay;
    f32x2 o; o.x = ax; o.y = ay;
    __builtin_nontemporal_store(
        o, reinterpret_cast<f32x2*>(out) + (long long)wave * 64 + lane);
}

// ---------------- R3 fallback: f32 gather ----------------

__global__ void build_nodes_kernel(const int* __restrict__ row,
                                   const int* __restrict__ col,
                                   const float* __restrict__ val,
                                   int E,
                                   int* __restrict__ head,
                                   int4* __restrict__ node) {
    int stride = gridDim.x * blockDim.x;
    for (int i = blockIdx.x * blockDim.x + threadIdx.x; i < E; i += stride) {
        int   r = row[i];
        int   c = col[i];
        float v = val[i];
        int prev = atomicExch(&head[r * NCHAIN + (i & (NCHAIN - 1))], i);
        node[i] = make_int4(prev, c, __float_as_int(v), 0);
    }
}

__global__ void __launch_bounds__(256)
reduce_nodes_kernel(const int* __restrict__ head,
                    const int4* __restrict__ node,
                    const float* __restrict__ embeds,
                    float* __restrict__ out,
                    int N) {
    int wave = (int)((blockIdx.x * (long long)blockDim.x + threadIdx.x) >> 6);
    int lane = threadIdx.x & 63;
    if (wave >= N) return;

    const float2* eb = reinterpret_cast<const float2*>(embeds);
    int4 h = reinterpret_cast<const int4*>(head)[wave];
    int e0 = h.x, e1 = h.y, e2 = h.z, e3 = h.w;

    float ax = 0.f, ay = 0.f;

    while ((e0 & e1 & e2 & e3) != -1) {
        int i0 = e0 >= 0 ? e0 : 0;
        int i1 = e1 >= 0 ? e1 : 0;
        int i2 = e2 >= 0 ? e2 : 0;
        int i3 = e3 >= 0 ? e3 : 0;

        int4 n0 = node[i0];
        int4 n1 = node[i1];
        int4 n2 = node[i2];
        int4 n3 = node[i3];

        int c0 = e0 >= 0 ? n0.y : 0;
        int c1 = e1 >= 0 ? n1.y : 0;
        int c2 = e2 >= 0 ? n2.y : 0;
        int c3 = e3 >= 0 ? n3.y : 0;

        float2 m0 = eb[(long long)c0 * 64 + lane];
        float2 m1 = eb[(long long)c1 * 64 + lane];
        float2 m2 = eb[(long long)c2 * 64 + lane];
        float2 m3 = eb[(long long)c3 * 64 + lane];

        float v0 = e0 >= 0 ? __int_as_float(n0.z) : 0.f;
        float v1 = e1 >= 0 ? __int_as_float(n1.z) : 0.f;
        float v2 = e2 >= 0 ? __int_as_float(n2.z) : 0.f;
        float v3 = e3 >= 0 ? __int_as_float(n3.z) : 0.f;

        ax += v0 * m0.x; ay += v0 * m0.y;
        ax += v1 * m1.x; ay += v1 * m1.y;
        ax += v2 * m2.x; ay += v2 * m2.y;
        ax += v3 * m3.x; ay += v3 * m3.y;

        e0 = e0 >= 0 ? n0.x : -1;
        e1 = e1 >= 0 ? n1.x : -1;
        e2 = e2 >= 0 ? n2.x : -1;
        e3 = e3 >= 0 ? n3.x : -1;
    }

    ax = ax > 0.f ? ax : LEAKY_SLOPE * ax;
    ay = ay > 0.f ? ay : LEAKY_SLOPE * ay;
    reinterpret_cast<float2*>(out)[(long long)wave * 64 + lane] =
        make_float2(ax, ay);
}

// ---------------- R0 fallback: atomic scatter ----------------

__global__ void gcn_scatter_kernel(const int* __restrict__ row_idx,
                                   const int* __restrict__ col_idx,
                                   const float* __restrict__ vals,
                                   const float* __restrict__ embeds,
                                   float* __restrict__ out,
                                   int E) {
    long long tid = (long long)blockIdx.x * blockDim.x + threadIdx.x;
    long long e = tid >> 5;
    if (e >= E) return;
    int q = (int)(tid & 31);
    int row = row_idx[e];
    int col = col_idx[e];
    float v = vals[e];
    const float4* src =
        reinterpret_cast<const float4*>(embeds + (long long)col * GCN_D) + q;
    float4 m = *src;
    float* dst = out + (long long)row * GCN_D + (long long)q * 4;
    atomicAdd(dst + 0, v * m.x);
    atomicAdd(dst + 1, v * m.y);
    atomicAdd(dst + 2, v * m.z);
    atomicAdd(dst + 3, v * m.w);
}

__global__ void gcn_leaky_relu_kernel(float* __restrict__ out, int n4) {
    int i = blockIdx.x * blockDim.x + threadIdx.x;
    if (i >= n4) return;
    float4* p = reinterpret_cast<float4*>(out) + i;
    float4 x = *p;
    x.x = x.x > 0.f ? x.x : LEAKY_SLOPE * x.x;
    x.y = x.y > 0.f ? x.y : LEAKY_SLOPE * x.y;
    x.z = x.z > 0.f ? x.z : LEAKY_SLOPE * x.z;
    x.w = x.w > 0.f ? x.w : LEAKY_SLOPE * x.w;
    *p = x;
}

// ---------------------------------------------------------------------------

extern "C" void kernel_launch(void* const* d_in, const int* in_sizes, int n_in,
                              void* d_out, int out_size, void* d_ws, size_t ws_size,
                              hipStream_t stream) {
    const int*   edge_index = (const int*)d_in[0];   // (2, E) flat, int32
    const float* edge_vals  = (const float*)d_in[1]; // (E,)
    const float* embeds     = (const float*)d_in[2]; // (N, 128) f32
    float*       out        = (float*)d_out;         // (N, 128) f32

    const int E = in_sizes[1];
    const int N = out_size / GCN_D;                  // 100000
    const int* row = edge_index;
    const int* col = edge_index + E;

    const int block = 256;

    // R4 ws layout: head[N*NCHAIN] | node[E] int4 | half-embeds[N*128] f16
    size_t head_b  = (size_t)N * NCHAIN * sizeof(int);      // 1.6 MB
    size_t node_b  = (size_t)E * sizeof(int4);              // 51.2 MB
    size_t half_b  = (size_t)N * GCN_D * sizeof(__half);    // 25.6 MB
    size_t need_r4 = head_b + node_b + half_b;
    size_t need_r3 = head_b + node_b;
    size_t need_r2 = (size_t)N * sizeof(int) + (size_t)E * sizeof(int);
    (void)need_r2;

    if (ws_size >= need_r4) {
        int*   head = (int*)d_ws;
        i32x4* node = reinterpret_cast<i32x4*>((char*)d_ws + head_b);
        u32x4* h8   = reinterpret_cast<u32x4*>((char*)d_ws + head_b + node_b);

        hipMemsetAsync(head, 0xFF, head_b, stream);

        int n8 = N * (GCN_D / 8);                     // 1.6M groups of 8 floats
        int convBlocks  = (n8 + block - 1) / block;   // 6250
        int buildBlocks = 2048;
        build_convert_kernel<<<convBlocks + buildBlocks, block, 0, stream>>>(
            row, col, edge_vals, E,
            reinterpret_cast<const f32x4*>(embeds), n8, h8,
            head, node, convBlocks);

        long long threads = (long long)N * 64;        // one wave per row
        int rblocks = (int)((threads + block - 1) / block);
        reduce_half_kernel<<<rblocks, block, 0, stream>>>(
            head, node, reinterpret_cast<const __half2*>(h8), out, N);
    } else if (ws_size >= need_r3) {
        int*  head = (int*)d_ws;
        int4* node = reinterpret_cast<int4*>((char*)d_ws + head_b);

        hipMemsetAsync(head, 0xFF, head_b, stream);
        build_nodes_kernel<<<2048, block, 0, stream>>>(row, col, edge_vals,
                                                       E, head, node);

        long long threads = (long long)N * 64;
        int rblocks = (int)((threads + block - 1) / block);
        reduce_nodes_kernel<<<rblocks, block, 0, stream>>>(
            head, node, embeds, out, N);
    } else {
        hipMemsetAsync(d_out, 0, (size_t)out_size * sizeof(float), stream);
        long long total_threads = (long long)E * 32;
        long long grid = (total_threads + block - 1) / block;
        gcn_scatter_kernel<<<(unsigned)grid, block, 0, stream>>>(
            row, col, edge_vals, embeds, out, E);
        int n4 = out_size / 4;
        gcn_leaky_relu_kernel<<<(n4 + 255) / 256, 256, 0, stream>>>(out, n4);
    }
}